// Round 11
// baseline (208.892 us; speedup 1.0000x reference)
//
#include <hip/hip_runtime.h>

// SimplePitchEstimator on MI355X (gfx950).
// Round-11: DIAGNOSTIC round. Kernel = exact round-10 (best, ~33 us, absmax 0)
// PLUS a probe kernel that isolates the conv phase with full counters.
//
// Why: pitch_kernel sits below the harness's 42-us fillBuffer wall, so no
// counters for 3 rounds; three competing theories (issue-bound conv /
// stall-bound conv / persistent 64-VGPR spill) predict the same total but
// different probe signatures:
//   issue-bound: probe ~70-90 us, VALUBusy >= 80%, WRITE ~0.3 MB
//   stall-bound: probe ~150+ us, VALUBusy 30-50%
//   spilling:    VGPR_Count == 64 and WRITE_SIZE >> 1 MB
// Probe = same LDS layout, same 4-wave paired conv_tiles, repeated 8x with a
// per-rep LDS perturbation + barriers (prevents hoisting); result -> d_ws.

#define SR_F    16000.0f
#define HOPSZ   256
#define TFRAMES 4096
#define SAMPLES 1048576

// Tile: lags N0..N0+14 via half-sum. col4 = X4 + f (quad q at col4[q*64]),
// colf = (float*)X4 + 4*f (row R at colf[(R/4)*256 + (R&3)]).
template<int N0>
__device__ __forceinline__ void conv_tile(const float4* __restrict__ col4,
                                          const float* __restrict__ colf,
                                          float& best, int& bl) {
    constexpr int J    = 15;
    constexpr int B0   = ((N0 - 3) / 4) * 4;   // window base row (aligned)
    constexpr int Q0   = B0 / 4;               // base quad
    constexpr int KOFF = N0 - B0;              // FMA index offset, 3..6
    constexpr int IC   = (N0 + 14 + 1) / 2;    // i-count for max lag
    constexpr int RT   = (IC + 3) / 4;         // total rounds
    constexpr int RC   = (N0 - 6 + 7) / 8;     // first ragged round
    static_assert(RC >= 1 && RC <= RT - 1, "clean/ragged split");
    static_assert(Q0 - (RT - 1) >= 0, "refill quad in range");
    static_assert(KOFF + J - 1 <= 20, "window index bound");

    float acc[J];
    #pragma unroll
    for (int j = 0; j < J; ++j) acc[j] = 0.f;

    // ---- window init: rows B0..B0+23 (clip quads > 39; w[21..23] unused) ----
    float w[24];
    #pragma unroll
    for (int i = 0; i < 6; ++i) {
        float4 q = (Q0 + i <= 39) ? col4[(Q0 + i) * 64]
                                  : make_float4(0.f, 0.f, 0.f, 0.f);
        w[4*i+0] = q.x; w[4*i+1] = q.y; w[4*i+2] = q.z; w[4*i+3] = q.w;
    }
    float4 xc = col4[0];                       // x quad for round 0

#define TILE_FMA_CLEAN                                                   \
    _Pragma("unroll")                                                    \
    for (int d = 0; d < 4; ++d) {                                        \
        const float xv = d == 0 ? xc.x : d == 1 ? xc.y                   \
                       : d == 2 ? xc.z : xc.w;                           \
        _Pragma("unroll")                                                \
        for (int j = 0; j < J; ++j)                                      \
            acc[j] = fmaf(xv, w[KOFF + j - d], acc[j]);                  \
    }

#define TILE_SHIFT_INSERT                                                \
    _Pragma("unroll")                                                    \
    for (int t = 23; t >= 4; --t) w[t] = w[t - 4];                       \
    w[0] = wn.x; w[1] = wn.y; w[2] = wn.z; w[3] = wn.w;

    // ---- clean rounds r = 0..RC-1 (all terms valid; prefetch r+1) ----
    #pragma unroll 1
    for (int r = 0; r < RC; ++r) {
        float4 xn = col4[(r + 1) * 64];            // x quad, round r+1
        float4 wn = col4[(Q0 - (r + 1)) * 64];     // refill quad, round r+1
        TILE_FMA_CLEAN
        TILE_SHIFT_INSERT
        xc = xn;
    }

    // ---- static tail r = RC..RT-1: masked FMAs (8r+2d < N0+j), same flow ----
    #pragma unroll
    for (int u = 0; u < RT - RC; ++u) {
        const int r = RC + u;                      // constant after unroll
        #pragma unroll
        for (int d = 0; d < 4; ++d) {
            const float xv = d == 0 ? xc.x : d == 1 ? xc.y
                           : d == 2 ? xc.z : xc.w;
            #pragma unroll
            for (int j = 0; j < J; ++j)
                if (8 * r + 2 * d < N0 + j)        // compile-time prune
                    acc[j] = fmaf(xv, w[KOFF + j - d], acc[j]);
        }
        if (r + 1 < RT) {                          // compile-time guard
            float4 wn = col4[(Q0 - (r + 1)) * 64];
            TILE_SHIFT_INSERT
            xc = col4[(r + 1) * 64];
        }
    }
#undef TILE_FMA_CLEAN
#undef TILE_SHIFT_INSERT

    // ---- finalize: x2 + center term (read from LDS), local argmax ----
    #pragma unroll
    for (int j = 0; j < J; ++j) {
        float v2 = acc[j] + acc[j];
        if ((N0 + j) % 2 == 0) {
            const int R = (N0 + j) / 2;            // constant after unroll
            const float c = colf[(R / 4) * 256 + (R & 3)];
            v2 = fmaf(c, c, v2);
        }
        if (v2 > best) { best = v2; bl = N0 + j; } // strict >: first max
    }
}

__device__ __forceinline__ void conv_pairs(int s, const float4* col4,
                                           const float* colf,
                                           float& best, int& bl) {
    if      (s == 0) { conv_tile< 40>(col4, colf, best, bl);
                       conv_tile<145>(col4, colf, best, bl); }
    else if (s == 1) { conv_tile< 55>(col4, colf, best, bl);
                       conv_tile<130>(col4, colf, best, bl); }
    else if (s == 2) { conv_tile< 70>(col4, colf, best, bl);
                       conv_tile<115>(col4, colf, best, bl); }
    else             { conv_tile< 85>(col4, colf, best, bl);
                       conv_tile<100>(col4, colf, best, bl); }
}

__global__ __launch_bounds__(256)
void pitch_kernel(const float* __restrict__ audio, float* __restrict__ out) {
    __shared__ float4 X4[40 * 64];                 // 40960 B exactly
    float* Xa = reinterpret_cast<float*>(X4);

    const int tid = threadIdx.x;
    const int s   = tid >> 6;          // wave id
    const int f   = tid & 63;          // frame within block
    const int blk = blockIdx.x;
    const int b   = blk >> 6;          // batch row
    const int t0  = (blk & 63) << 6;   // first frame of block

    // ---- Phase A: load 40 samples of frame f (chunk s), partial sum ----
    const float* g = audio + (size_t)b * SAMPLES + (size_t)(t0 + f) * HOPSZ + s * 40;
    float v[40];
    float ps = 0.f;
    #pragma unroll
    for (int j = 0; j < 10; ++j) {
        float4 q = reinterpret_cast<const float4*>(g)[j];   // 16B-aligned
        v[4*j+0] = q.x; v[4*j+1] = q.y; v[4*j+2] = q.z; v[4*j+3] = q.w;
        ps += q.x + q.y + q.z + q.w;
    }

    // ---- Phase B: block mean via aux ----
    Xa[s * 64 + f] = ps;
    __syncthreads();
    const float mu = (Xa[f] + Xa[64 + f] + Xa[128 + f] + Xa[192 + f]) * (1.0f / 160.0f);
    float pm = 0.f;
    #pragma unroll
    for (int q = 0; q < 40; ++q) pm = fmaxf(pm, fabsf(v[q] - mu));
    __syncthreads();                       // sum-reads done

    // ---- Phase C: silent-check partial max via aux ----
    Xa[s * 64 + f] = pm;
    __syncthreads();
    float mx = 0.f;
    if (s == 0)
        mx = fmaxf(fmaxf(Xa[f], Xa[64 + f]), fmaxf(Xa[128 + f], Xa[192 + f]));
    __syncthreads();                       // pm-reads done

    // ---- Phase D: write centered frames as row-quads (b128, contiguous) ----
    #pragma unroll
    for (int k = 0; k < 10; ++k)
        X4[(10 * s + k) * 64 + f] =
            make_float4(v[4*k+0] - mu, v[4*k+1] - mu, v[4*k+2] - mu, v[4*k+3] - mu);
    __syncthreads();

    // ---- Phase E: paired balanced tiles (rounds 27/27/28/28) ----
    const float4* col4 = X4 + f;
    const float*  colf = Xa + 4 * f;
    float best = -3.4e38f; int bl = 0;
    conv_pairs(s, col4, colf, best, bl);
    __syncthreads();                       // conv done: X now dead

    // ---- Phase F: cross-wave argmax via aux ----
    Xa[s * 64 + f] = best;
    reinterpret_cast<int*>(Xa)[256 + s * 64 + f] = bl;
    __syncthreads();

    if (s == 0) {
        float bv = Xa[f];
        int   L  = reinterpret_cast<int*>(Xa)[256 + f];
        #pragma unroll
        for (int c = 1; c < 4; ++c) {
            const float vv = Xa[c * 64 + f];
            const int   lv = reinterpret_cast<int*>(Xa)[256 + c * 64 + f];
            if (vv > bv || (vv == bv && lv < L)) { bv = vv; L = lv; }
        }
        const float pitch = SR_F / (float)L;
        out[(size_t)b * TFRAMES + t0 + f] = (mx < 1e-8f) ? 0.0f : pitch;
    }
}

// ---- Probe: conv phase only, repeated 8x, full counters. Writes to d_ws. ----
__global__ __launch_bounds__(256)
void probe_kernel(float* __restrict__ ws) {
    __shared__ float4 X4[40 * 64];                 // same 40960 B footprint
    float* Xa = reinterpret_cast<float*>(X4);

    const int tid = threadIdx.x;
    const int s   = tid >> 6;
    const int f   = tid & 63;

    // deterministic fill (values irrelevant for fp32 timing; keep sane range)
    #pragma unroll
    for (int k = 0; k < 10; ++k) {
        const float base = 0.013f * f + 0.07f * k - 0.4f;
        X4[(10 * s + k) * 64 + f] =
            make_float4(base, base + 0.011f, base - 0.017f, base + 0.005f);
    }
    __syncthreads();

    float best = -3.4e38f; int bl = 0;
    const float4* col4 = X4 + f;
    const float*  colf = Xa + 4 * f;

    #pragma unroll 1
    for (int rep = 0; rep < 8; ++rep) {
        // perturb LDS each rep so the 8 reps cannot be collapsed/hoisted
        if (tid == 0) Xa[0] = 0.5f + 1e-6f * (float)rep;
        __syncthreads();
        conv_pairs(s, col4, colf, best, bl);
        __syncthreads();
    }

    if (tid == 0) ws[blockIdx.x] = best + (float)bl;
}

extern "C" void kernel_launch(void* const* d_in, const int* in_sizes, int n_in,
                              void* d_out, int out_size, void* d_ws, size_t ws_size,
                              hipStream_t stream) {
    const float* audio = (const float*)d_in[0];
    float* out = (float*)d_out;
    pitch_kernel<<<dim3(1024), dim3(256), 0, stream>>>(audio, out);
    if (ws_size >= 1024 * sizeof(float))   // constant per session: graph-safe
        probe_kernel<<<dim3(1024), dim3(256), 0, stream>>>((float*)d_ws);
}

// Round 12
// 96.724 us; speedup vs baseline: 2.1597x; 2.1597x over previous
//
#include <hip/hip_runtime.h>

// SimplePitchEstimator on MI355X (gfx950).
// ac = irfft(rfft(x,512)^2) == linear self-convolution c[n] = sum y[i]y[n-i],
// y = x - mean(x). Round-12: r9's zero-mov rotation conv + plain
// __launch_bounds__(256).
//
// Evidence chain: r11 probe measured conv = 16.3 us, VALUBusy 86.7%, no
// spill, VGPR 88 -> issue-bound at ~145 VALU-instr per 60-FMA round (the
// w[24] shift-window codegen). r9's named-var quad rotation eliminates ALL
// window-maintenance movs (~70 instr/round) but was built with
// waves_per_eu(4,4) -> 64-VGPR pin -> spilled (VGPR=64, WRITE 75 MB).
// r11 proves plain __launch_bounds__(256) grants 88+. Single change here:
// rotation conv + plain bounds. Expected conv 16.3 -> 8-11 us.
//
//  * Six NAMED float4 vars W0..W5 hold the 6 window quads; quad->var map
//    (quad % 6) repeats every 6 rounds -> clean loop unrolled x6; every
//    reference is a static component of a named var (no array).
//  * Refill ds_read_b128 directly into the rotating target var, placed
//    after the round's FMAs (latency covered by next round); x quads via
//    2-var ping-pong (trip length 6 even -> static parity).
//  * Remainder + ragged rounds statically unrolled, affine masks
//    8r+2d < N0+j.
//  * Half-sum c[n] = 2*sum_{2i<n} y_i y_{n-i} + center (validated r6-r10).
//  * LDS 160x64x4 = 40960 B exactly (4 blocks/CU, 1024 blocks co-resident);
//    balanced tile pairs 27/27/28/28; mu folded at LDS write; silent-check
//    pm rides in a register to the final reduction (no phase C).

#define SR_F    16000.0f
#define HOPSZ   256
#define TFRAMES 4096
#define SAMPLES 1048576

#define CMP(v_, c_) ((c_) == 0 ? (v_).x : (c_) == 1 ? (v_).y : \
                     (c_) == 2 ? (v_).z : (v_).w)

template<int N0>
__device__ __forceinline__ void conv_tile(const float4* __restrict__ col4,
                                          const float* __restrict__ colf,
                                          float& best, int& bl) {
    constexpr int J    = 15;
    constexpr int B0   = ((N0 - 3) / 4) * 4;   // aligned window base row
    constexpr int Q0   = B0 / 4;               // base quad at round 0
    constexpr int KOFF = N0 - B0;              // 3..6
    constexpr int IC   = (N0 + J) / 2;         // i-count for max lag
    constexpr int RT   = (IC + 3) / 4;         // total rounds
    constexpr int RC   = (N0 - 6 + 7) / 8;     // clean rounds (8r+6 < N0)
    constexpr int T    = RC / 6;               // runtime x6 trips
    constexpr int R6   = 6 * T;                // first static round
    static_assert(KOFF >= 3 && KOFF + J - 1 <= 20, "window index bound");
    static_assert(RC >= 1 && RC <= RT - 1, "clean/ragged split");
    static_assert(Q0 - RT + 1 >= 0, "refill quad in range");

    float acc[J];
    #pragma unroll
    for (int j = 0; j < J; ++j) acc[j] = 0.f;

    float4 W0_, W1_, W2_, W3_, W4_, W5_, xa_, xb_;

#define WREAD(vi_, c_) \
    ((vi_) == 0 ? CMP(W0_, c_) : (vi_) == 1 ? CMP(W1_, c_) : \
     (vi_) == 2 ? CMP(W2_, c_) : (vi_) == 3 ? CMP(W3_, c_) : \
     (vi_) == 4 ? CMP(W4_, c_) : CMP(W5_, c_))

#define WSTORE(vi_, e_) do {                                              \
    if      ((vi_) == 0) W0_ = (e_); else if ((vi_) == 1) W1_ = (e_);     \
    else if ((vi_) == 2) W2_ = (e_); else if ((vi_) == 3) W3_ = (e_);     \
    else if ((vi_) == 4) W4_ = (e_); else                 W5_ = (e_);     \
    } while (0)

    // round with round-index R_ (mask/parity) and rotation phase K_ (=R_ mod 6
    // folded statically); MASKED_=1 enables the ragged-term prune.
#define ROUND_BODY(K_, R_, MASKED_)                                       \
    {                                                                     \
        const float4 xc = ((R_) & 1) ? xb_ : xa_;                         \
        _Pragma("unroll")                                                 \
        for (int d = 0; d < 4; ++d) {                                     \
            const float xv = CMP(xc, d);                                  \
            _Pragma("unroll")                                             \
            for (int j = 0; j < J; ++j) {                                 \
                if (!(MASKED_) || (8 * (R_) + 2 * d < N0 + j)) {          \
                    const int g  = KOFF + j - d;                          \
                    const int vi = ((Q0 + g / 4 - (K_)) % 6 + 6) % 6;     \
                    acc[j] = fmaf(xv, WREAD(vi, g & 3), acc[j]);          \
                }                                                         \
            }                                                             \
        }                                                                 \
    }

    // ---- init: quads Q0..Q0+5 into vars (Q0+i)%6 (clip quads>39), x quad 0
    #pragma unroll
    for (int i = 0; i < 6; ++i) {
        const float4 q = (Q0 + i <= 39) ? col4[(Q0 + i) * 64]
                                        : make_float4(0.f, 0.f, 0.f, 0.f);
        WSTORE((Q0 + i) % 6, q);
    }
    xa_ = col4[0];

    // ---- runtime x6 trips: rounds r = 6t+k, all clean ----
    const float4* xq = col4;                 // x base: quad 6t
    const float4* wq = col4 + Q0 * 64;       // refill base: quad Q0-6t
    #pragma unroll 1
    for (int t = 0; t < T; ++t) {
        #pragma unroll
        for (int k = 0; k < 6; ++k) {
            if (((k + 1) & 1) == 0) xa_ = xq[(k + 1) * 64];
            else                    xb_ = xq[(k + 1) * 64];
            ROUND_BODY(k, k, 0)
            // refill quad Q0-6t-k-1 -> var just freed this round
            WSTORE(((Q0 - k - 1) % 6 + 6) % 6, wq[-(k + 1) * 64]);
        }
        xq += 6 * 64;
        wq -= 6 * 64;
    }

    // ---- static rounds rr = R6..RT-1 (clean remainder + ragged) ----
    #pragma unroll
    for (int u = 0; u < RT - R6; ++u) {
        const int rr = R6 + u;                       // constant after unroll
        if (rr + 1 < RT) {                           // compile-time guard
            if (((rr + 1) & 1) == 0) xa_ = col4[(rr + 1) * 64];
            else                     xb_ = col4[(rr + 1) * 64];
        }
        ROUND_BODY(rr, rr, (rr >= RC))
        if (rr + 1 < RT)
            WSTORE(((Q0 - rr - 1) % 6 + 6) % 6, col4[(Q0 - rr - 1) * 64]);
    }

    // ---- finalize: x2 + center term for even lags, local argmax ----
    #pragma unroll
    for (int j = 0; j < J; ++j) {
        float v2 = acc[j] + acc[j];
        if ((N0 + j) % 2 == 0) {
            const int R = (N0 + j) / 2;              // constant after unroll
            const float c = colf[(R / 4) * 256 + (R & 3)];
            v2 = fmaf(c, c, v2);
        }
        if (v2 > best) { best = v2; bl = N0 + j; }   // strict >: first max
    }
#undef ROUND_BODY
#undef WSTORE
#undef WREAD
}

__global__ __launch_bounds__(256)
void pitch_kernel(const float* __restrict__ audio, float* __restrict__ out) {
    __shared__ float4 X4[40 * 64];                   // 40960 B exactly
    float* Xa = reinterpret_cast<float*>(X4);

    const int tid = threadIdx.x;
    const int s   = tid >> 6;          // wave id
    const int f   = tid & 63;          // frame within block
    const int blk = blockIdx.x;
    const int b   = blk >> 6;          // batch row
    const int t0  = (blk & 63) << 6;   // first frame of block

    // ---- Phase A: load 40 samples of frame f (chunk s), partial sum ----
    const float* g = audio + (size_t)b * SAMPLES + (size_t)(t0 + f) * HOPSZ + s * 40;
    float v[40];
    float ps = 0.f;
    #pragma unroll
    for (int j = 0; j < 10; ++j) {
        float4 q = reinterpret_cast<const float4*>(g)[j];   // 16B-aligned
        v[4*j+0] = q.x; v[4*j+1] = q.y; v[4*j+2] = q.z; v[4*j+3] = q.w;
        ps += q.x + q.y + q.z + q.w;
    }

    // ---- Phase B: block mean via aux rows; pm stays in a register ----
    Xa[s * 64 + f] = ps;
    __syncthreads();
    const float mu = (Xa[f] + Xa[64 + f] + Xa[128 + f] + Xa[192 + f]) * (1.0f / 160.0f);
    float pm = 0.f;
    #pragma unroll
    for (int q = 0; q < 40; ++q) pm = fmaxf(pm, fabsf(v[q] - mu));
    __syncthreads();                       // sum-reads done before D overwrites

    // ---- Phase D: write centered frames as row-quads (b128, contiguous) ----
    #pragma unroll
    for (int k = 0; k < 10; ++k)
        X4[(10 * s + k) * 64 + f] =
            make_float4(v[4*k+0] - mu, v[4*k+1] - mu, v[4*k+2] - mu, v[4*k+3] - mu);
    __syncthreads();

    // ---- Phase E: paired balanced tiles (rounds 27/27/28/28) ----
    const float4* col4 = X4 + f;
    const float*  colf = Xa + 4 * f;
    float best = -3.4e38f; int bl = 0;
    if      (s == 0) { conv_tile< 40>(col4, colf, best, bl);
                       conv_tile<145>(col4, colf, best, bl); }
    else if (s == 1) { conv_tile< 55>(col4, colf, best, bl);
                       conv_tile<130>(col4, colf, best, bl); }
    else if (s == 2) { conv_tile< 70>(col4, colf, best, bl);
                       conv_tile<115>(col4, colf, best, bl); }
    else             { conv_tile< 85>(col4, colf, best, bl);
                       conv_tile<100>(col4, colf, best, bl); }
    __syncthreads();                       // conv done: X now dead

    // ---- Phase F: cross-wave argmax + silent-check via aux rows ----
    Xa[s * 64 + f] = best;
    reinterpret_cast<int*>(Xa)[256 + s * 64 + f] = bl;
    Xa[512 + s * 64 + f] = pm;
    __syncthreads();

    if (s == 0) {
        float bv = Xa[f];
        int   L  = reinterpret_cast<int*>(Xa)[256 + f];
        #pragma unroll
        for (int c = 1; c < 4; ++c) {
            const float vv = Xa[c * 64 + f];
            const int   lv = reinterpret_cast<int*>(Xa)[256 + c * 64 + f];
            if (vv > bv || (vv == bv && lv < L)) { bv = vv; L = lv; }
        }
        const float mx = fmaxf(fmaxf(Xa[512 + f], Xa[512 + 64 + f]),
                               fmaxf(Xa[512 + 128 + f], Xa[512 + 192 + f]));
        const float pitch = SR_F / (float)L;
        out[(size_t)b * TFRAMES + t0 + f] = (mx < 1e-8f) ? 0.0f : pitch;
    }
}

extern "C" void kernel_launch(void* const* d_in, const int* in_sizes, int n_in,
                              void* d_out, int out_size, void* d_ws, size_t ws_size,
                              hipStream_t stream) {
    const float* audio = (const float*)d_in[0];
    float* out = (float*)d_out;
    pitch_kernel<<<dim3(1024), dim3(256), 0, stream>>>(audio, out);
}